// Round 9
// baseline (1051.589 us; speedup 1.0000x reference)
//
#include <hip/hip_runtime.h>
#include <cstdint>

#define DEV __device__ __forceinline__

typedef unsigned short u16;
typedef __attribute__((ext_vector_type(8))) short bf16x8;   // 8 bf16 = 4 VGPRs (MFMA A/B frag)
typedef __attribute__((ext_vector_type(4))) unsigned short u16x4;
typedef __attribute__((ext_vector_type(4))) float f32x4;    // MFMA C/D frag

typedef __attribute__((address_space(1))) const void GV;
typedef __attribute__((address_space(3))) void LV;

DEV float b2f(u16 u) { uint32_t i = ((uint32_t)u) << 16; return __builtin_bit_cast(float, i); }
DEV u16 f2b(float f) {
    uint32_t i = __builtin_bit_cast(uint32_t, f);
    return (u16)((i + 0x7fffu + ((i >> 16) & 1u)) >> 16);   // RNE
}
DEV void load_lds16(const void* g, void* l) {
    // dest = wave-uniform LDS base + lane*16B; src is per-lane global, 16B contiguous
    __builtin_amdgcn_global_load_lds((GV*)g, (LV*)l, 16, 0, 0);
}

// ---------------------------------------------------------------- elementwise
__global__ __launch_bounds__(256) void k_addpos(const float* __restrict__ x,
                                                const float* __restrict__ pos,
                                                float* __restrict__ h) {
    size_t i = (size_t)blockIdx.x * 256 + threadIdx.x;
    f32x4 a = *(const f32x4*)(x + i * 4);
    f32x4 p = *(const f32x4*)(pos + ((i * 4) & 1048575));
    a += p;
    *(f32x4*)(h + i * 4) = a;
}

// fp32 [K][N] -> bf16 [N][K] (transposed); in z-stride K*N, out z-stride ozs
__global__ __launch_bounds__(256) void k_transcvt(const float* __restrict__ W,
                                                  u16* __restrict__ WT, int K, int N,
                                                  size_t ozs) {
    __shared__ float t[32][33];
    size_t zin = (size_t)blockIdx.z * K * N, zout = (size_t)blockIdx.z * ozs;
    int n0 = blockIdx.x * 32, k0 = blockIdx.y * 32;
    int r = threadIdx.x >> 3, c = (threadIdx.x & 7) << 2;
    f32x4 v = *(const f32x4*)(W + zin + (size_t)(k0 + r) * N + n0 + c);
    t[r][c] = v[0]; t[r][c + 1] = v[1]; t[r][c + 2] = v[2]; t[r][c + 3] = v[3];
    __syncthreads();
    u16x4 o;
    o[0] = f2b(t[c][r]); o[1] = f2b(t[c + 1][r]); o[2] = f2b(t[c + 2][r]); o[3] = f2b(t[c + 3][r]);
    *(u16x4*)(WT + zout + (size_t)(n0 + r) * K + k0 + c) = o;
}

// fp32 -> bf16 flat convert (head weights)
__global__ __launch_bounds__(256) void k_cvt(const float* __restrict__ in,
                                             u16* __restrict__ out, int n4) {
    int i = blockIdx.x * 256 + threadIdx.x;
    if (i < n4) {
        f32x4 v = *(const f32x4*)(in + (size_t)i * 4);
        u16x4 o; o[0] = f2b(v[0]); o[1] = f2b(v[1]); o[2] = f2b(v[2]); o[3] = f2b(v[3]);
        *(u16x4*)(out + (size_t)i * 4) = o;
    }
}

// pack per-layer q/k/v biases into [L][3072]
__global__ __launch_bounds__(256) void k_packb(const float* __restrict__ bq,
                                               const float* __restrict__ bk,
                                               const float* __restrict__ bv,
                                               float* __restrict__ bqkv) {
    int l = blockIdx.x;
    for (int i = threadIdx.x; i < 1024; i += 256) {
        bqkv[l * 3072 + i]        = bq[l * 1024 + i];
        bqkv[l * 3072 + 1024 + i] = bk[l * 1024 + i];
        bqkv[l * 3072 + 2048 + i] = bv[l * 1024 + i];
    }
}

// ---------------------------------------------------------------- layernorm
__global__ __launch_bounds__(256) void k_ln(const float* __restrict__ in,
                                            const float* __restrict__ g,
                                            const float* __restrict__ bta,
                                            u16* __restrict__ out) {
    int row = blockIdx.x, tid = threadIdx.x;
    const float* rp = in + (size_t)row * 1024;
    f32x4 v = *(const f32x4*)(rp + tid * 4);
    float s = v[0] + v[1] + v[2] + v[3];
    float ss = v[0] * v[0] + v[1] * v[1] + v[2] * v[2] + v[3] * v[3];
    #pragma unroll
    for (int off = 32; off; off >>= 1) { s += __shfl_down(s, off); ss += __shfl_down(ss, off); }
    __shared__ float rs[4], rss[4];
    int wave = tid >> 6, lane = tid & 63;
    if (!lane) { rs[wave] = s; rss[wave] = ss; }
    __syncthreads();
    float ts = rs[0] + rs[1] + rs[2] + rs[3];
    float tss = rss[0] + rss[1] + rss[2] + rss[3];
    float mean = ts * (1.0f / 1024.0f);
    float var = tss * (1.0f / 1024.0f) - mean * mean;
    float rstd = rsqrtf(var + 1e-5f);
    f32x4 gv = *(const f32x4*)(g + tid * 4);
    f32x4 bv = *(const f32x4*)(bta + tid * 4);
    u16x4 o;
    #pragma unroll
    for (int j = 0; j < 4; ++j) o[j] = f2b((v[j] - mean) * rstd * gv[j] + bv[j]);
    *(u16x4*)(out + (size_t)row * 1024 + tid * 4) = o;
}

// ---------------------------------------------------------------- GEMM 64x128 (residual add)
// H[M][N] += A[M][K] @ BT[N][K]^T + bias. BM=64 BN=128 BK=64, 4 waves (2x2).
// T3/T4 pipeline: 3 LDS buffers, 2-tiles-ahead prefetch, raw s_barrier with
// counted s_waitcnt vmcnt(6) (6 loads/wave/stage stay in flight across the
// barrier; never drain to 0 in the loop). lgkmcnt(0)+sched_barrier before the
// MFMA cluster guarantees all ds_reads retired before the barrier (no race
// with the next iter's DMA into the 3rd buffer). XOR swizzle both-sides.
__global__ __launch_bounds__(256) void k_gemmr(const u16* __restrict__ A,
                                               const u16* __restrict__ BT,
                                               const float* __restrict__ bias,
                                               float* __restrict__ H,
                                               int M, int N, int K) {
    __shared__ __align__(16) u16 As[3][64 * 64];     // [m][k] swizzled
    __shared__ __align__(16) u16 Bs[3][128 * 64];    // [n][k] swizzled
    const int tid = threadIdx.x, lane = tid & 63, wave = tid >> 6;
    const int wy = wave >> 1, wx = wave & 1;
    const int lcol = lane & 15, lrow = lane >> 4;

    const int nbx = gridDim.x, nwg = nbx * gridDim.y;
    int id = blockIdx.y * nbx + blockIdx.x;
    int q = nwg >> 3, r = nwg & 7;
    int xcd = id & 7, pos = id >> 3;
    int nid = (xcd < r ? xcd * (q + 1) : r * (q + 1) + (xcd - r) * q) + pos;
    const int m0 = (nid / nbx) * 64, n0 = (nid % nbx) * 128;
    const int NT = K >> 6;

    f32x4 acc[2][4] = {};

    auto stage = [&](int bi, int kt) {               // 6 global_load_lds per thread
        int k0 = kt << 6;
        #pragma unroll
        for (int it = 0; it < 2; ++it) {             // A: 512 chunks (64 rows x 8 slots)
            int c = it * 256 + tid;
            int row = c >> 3, s = (c & 7) ^ (row & 7);
            load_lds16(A + (size_t)(m0 + row) * K + k0 + s * 8,
                       &As[bi][(it * 256 + wave * 64) * 8]);
        }
        #pragma unroll
        for (int it = 0; it < 4; ++it) {             // B: 1024 chunks (128 rows x 8 slots)
            int c = it * 256 + tid;
            int row = c >> 3, s = (c & 7) ^ (row & 7);
            load_lds16(BT + (size_t)(n0 + row) * K + k0 + s * 8,
                       &Bs[bi][(it * 256 + wave * 64) * 8]);
        }
    };

    stage(0, 0);
    if (NT > 1) stage(1, 1);
    asm volatile("s_waitcnt vmcnt(6)" ::: "memory"); // tile 0 landed; tile 1 in flight
    __builtin_amdgcn_sched_barrier(0);

    int cur = 0;
    for (int kt = 0; kt < NT; ++kt) {
        __builtin_amdgcn_s_barrier();                // buf[cur] ready; prev reads done
        if (kt + 2 < NT) {
            int nb = cur + 2; if (nb >= 3) nb -= 3;
            stage(nb, kt + 2);
        }
        const u16* ab = As[cur];
        const u16* bb = Bs[cur];
        bf16x8 af[2][2], bfr[2][4];
        #pragma unroll
        for (int kc = 0; kc < 2; ++kc) {
            #pragma unroll
            for (int mi = 0; mi < 2; ++mi) {
                int mrow = wy * 32 + mi * 16 + lcol;
                int s = (kc * 4 + lrow) ^ (mrow & 7);
                af[kc][mi] = *(const bf16x8*)(ab + mrow * 64 + s * 8);
            }
            #pragma unroll
            for (int ni = 0; ni < 4; ++ni) {
                int nrow = wx * 64 + ni * 16 + lcol;
                int s = (kc * 4 + lrow) ^ (nrow & 7);
                bfr[kc][ni] = *(const bf16x8*)(bb + nrow * 64 + s * 8);
            }
        }
        asm volatile("s_waitcnt lgkmcnt(0)" ::: "memory");   // all ds_reads retired
        __builtin_amdgcn_sched_barrier(0);
        __builtin_amdgcn_s_setprio(1);
        #pragma unroll
        for (int kc = 0; kc < 2; ++kc)
            #pragma unroll
            for (int mi = 0; mi < 2; ++mi)
                #pragma unroll
                for (int ni = 0; ni < 4; ++ni)
                    acc[mi][ni] = __builtin_amdgcn_mfma_f32_16x16x32_bf16(af[kc][mi], bfr[kc][ni], acc[mi][ni], 0, 0, 0);
        __builtin_amdgcn_s_setprio(0);
        if (kt + 2 < NT) { asm volatile("s_waitcnt vmcnt(6)" ::: "memory"); }  // next tile landed
        else             { asm volatile("s_waitcnt vmcnt(0)" ::: "memory"); }
        __builtin_amdgcn_sched_barrier(0);
        cur = cur + 1; if (cur >= 3) cur -= 3;
    }

    #pragma unroll
    for (int mi = 0; mi < 2; ++mi) {
        #pragma unroll
        for (int ni = 0; ni < 4; ++ni) {
            int col = n0 + wx * 64 + ni * 16 + lcol;
            float bcol = bias[col];
            #pragma unroll
            for (int r2 = 0; r2 < 4; ++r2) {
                int row = m0 + wy * 32 + mi * 16 + lrow * 4 + r2;
                float* o = H + (size_t)row * N + col;
                *o = *o + acc[mi][ni][r2] + bcol;
            }
        }
    }
}

// ---------------------------------------------------------------- GEMM 128x256
// 512 threads, 8 waves (2 m x 4 n), wave-tile 64x64, BK=32, dbuf (48 KB LDS ->
// 2+ blocks/CU co-resident hide 2-phase drains). XOR swizzle f(row)=(row>>1)&3
// both-sides. Bijective XCD block swizzle. EPI: 0 = bf16, 1 = gelu.
template <int EPI>
__global__ __launch_bounds__(512) void k_g128(const u16* __restrict__ A,
                                              const u16* __restrict__ BT,
                                              const float* __restrict__ bias,
                                              u16* __restrict__ Cout,
                                              int M, int N, int K) {
    __shared__ __align__(16) u16 As[2][4096];   // [128 m][32 k]
    __shared__ __align__(16) u16 Bs[2][8192];   // [256 n][32 k]
    const int tid = threadIdx.x, lane = tid & 63, wave = tid >> 6;
    const int wy = wave >> 2, wx = wave & 3;
    const int lcol = lane & 15, lrow = lane >> 4;

    const int nbx = gridDim.x, nwg = nbx * gridDim.y;
    int id = blockIdx.y * nbx + blockIdx.x;
    int q = nwg >> 3, r = nwg & 7;
    int xcd = id & 7, pos = id >> 3;
    int nid = (xcd < r ? xcd * (q + 1) : r * (q + 1) + (xcd - r) * q) + pos;
    const int m0 = (nid / nbx) * 128, n0 = (nid % nbx) * 256;
    const int NT = K >> 5;

    f32x4 acc[4][4] = {};

    auto stage = [&](int buf, int kt) {
        int k0 = kt << 5;
        {   // A: 512 chunks (128 rows x 4 slots), 1/thread
            int c = tid;
            int row = c >> 2, s = (c & 3) ^ ((row >> 1) & 3);
            load_lds16(A + (size_t)(m0 + row) * K + k0 + s * 8,
                       &As[buf][(wave * 64) * 8]);
        }
        #pragma unroll
        for (int it = 0; it < 2; ++it) {   // B: 1024 chunks (256 rows x 4 slots)
            int c = it * 512 + tid;
            int row = c >> 2, s = (c & 3) ^ ((row >> 1) & 3);
            load_lds16(BT + (size_t)(n0 + row) * K + k0 + s * 8,
                       &Bs[buf][(it * 512 + wave * 64) * 8]);
        }
    };

    stage(0, 0);
    for (int kt = 0; kt < NT; ++kt) {
        __syncthreads();
        if (kt + 1 < NT) stage((kt + 1) & 1, kt + 1);
        const u16* ab = As[kt & 1];
        const u16* bb = Bs[kt & 1];
        bf16x8 bfr[4];
        #pragma unroll
        for (int ni = 0; ni < 4; ++ni) {
            int nrow = wx * 64 + ni * 16 + lcol;
            bfr[ni] = *(const bf16x8*)(bb + nrow * 32 + ((lrow ^ ((nrow >> 1) & 3)) * 8));
        }
        #pragma unroll
        for (int mi = 0; mi < 4; ++mi) {
            int mrow = wy * 64 + mi * 16 + lcol;
            bf16x8 af = *(const bf16x8*)(ab + mrow * 32 + ((lrow ^ ((mrow >> 1) & 3)) * 8));
            #pragma unroll
            for (int ni = 0; ni < 4; ++ni)
                acc[mi][ni] = __builtin_amdgcn_mfma_f32_16x16x32_bf16(af, bfr[ni], acc[mi][ni], 0, 0, 0);
        }
    }

    #pragma unroll
    for (int mi = 0; mi < 4; ++mi) {
        #pragma unroll
        for (int ni = 0; ni < 4; ++ni) {
            int col = n0 + wx * 64 + ni * 16 + lcol;
            float bcol = bias[col];
            #pragma unroll
            for (int r2 = 0; r2 < 4; ++r2) {
                int row = m0 + wy * 64 + mi * 16 + lrow * 4 + r2;
                float val = acc[mi][ni][r2] + bcol;
                if constexpr (EPI == 1)
                    val = 0.5f * val * (1.0f + erff(val * 0.70710678118654752f));
                Cout[(size_t)row * N + col] = f2b(val);
            }
        }
    }
}

// ---------------------------------------------------------------- attention
// QKV fused input [4096][3072] bf16 (q|k|v per 1024 cols), head h at +h*128.
__global__ __launch_bounds__(256) void k_attn(const u16* __restrict__ qkv,
                                              const float* __restrict__ abias,
                                              u16* __restrict__ yb) {
    __shared__ __align__(16) u16 Ks[2][64 * 128];
    __shared__ __align__(16) u16 Vt[2][128 * 64];
    __shared__ __align__(16) u16 Ps[4][16 * 72];

    const int idx = blockIdx.x;
    const int half = idx >> 8, u = idx & 255;
    const int qt = half ? (15 - (u & 15)) : (u & 15);
    const int h = (u >> 4) & 7;
    const int b = (u >> 7) + half * 2;

    const int tid = threadIdx.x, wave = tid >> 6, lane = tid & 63;
    const int lcol = lane & 15, lrow = lane >> 4;
    const int q0 = qt * 64 + wave * 16;
    const size_t base = (size_t)b * 1024 * 3072 + h * 128;
    const u16* qp = qkv + base;
    const u16* kp = qkv + base + 1024;
    const u16* vp = qkv + base + 2048;
    u16* psw = Ps[wave];
    const int j4 = tid & 15, d8 = tid >> 4;

    bf16x8 aq[4];
    #pragma unroll
    for (int df = 0; df < 4; ++df)
        aq[df] = *(const bf16x8*)(qp + (size_t)(q0 + lcol) * 3072 + df * 32 + lrow * 8);

    f32x4 o[8];
    #pragma unroll
    for (int i = 0; i < 8; ++i) o[i] = f32x4{0.f, 0.f, 0.f, 0.f};
    float mrun[4], lrun[4];
    #pragma unroll
    for (int r = 0; r < 4; ++r) { mrun[r] = -__builtin_inff(); lrun[r] = 0.f; }

    const float scale = 0.08838834764831845f;
    const int nt = qt + 1;

    auto k_issue = [&](int buf, int t) {
        const int j0 = t * 64;
        #pragma unroll
        for (int it = 0; it < 4; ++it) {
            int c = it * 256 + wave * 64 + lane;
            int row = c >> 4, slot = c & 15;
            int sslot = slot ^ (row & 7);
            load_lds16(kp + (size_t)(j0 + row) * 3072 + sslot * 8,
                       &Ks[buf][(it * 256 + wave * 64) * 8]);
        }
    };
    auto v_issue = [&](int t, bf16x8* vr) {
        const int j0 = t * 64;
        #pragma unroll
        for (int r = 0; r < 4; ++r)
            vr[r] = *(const bf16x8*)(vp + (size_t)(j0 + j4 * 4 + r) * 3072 + d8 * 8);
    };
    auto v_write = [&](int buf, const bf16x8* vr) {
        #pragma unroll
        for (int i = 0; i < 8; ++i) {
            int d = d8 * 8 + i;
            u16x4 w;
            w[0] = (u16)vr[0][i]; w[1] = (u16)vr[1][i]; w[2] = (u16)vr[2][i]; w[3] = (u16)vr[3][i];
            *(u16x4*)(&Vt[buf][d * 64 + ((j4 * 4) ^ (i << 3))]) = w;
        }
    };

    bf16x8 v0r[4];
    k_issue(0, 0);
    v_issue(0, v0r);
    v_write(0, v0r);

    for (int t = 0; t < nt; ++t) {
        __syncthreads();
        const int cur = t & 1, nxt = cur ^ 1;
        const bool more = (t + 1 < nt);
        bf16x8 vn[4];
        if (more) { k_issue(nxt, t + 1); v_issue(t + 1, vn); }

        const u16* ks = Ks[cur];
        const u16* vt = Vt[cur];
        const int j0 = t * 64;

        f32x4 S[4];
        #pragma unroll
        for (int sub = 0; sub < 4; ++sub) {
            const int row = sub * 16 + lcol;
            const int sw = row & 7;
            f32x4 s = {};
            #pragma unroll
            for (int df = 0; df < 4; ++df) {
                bf16x8 kf = *(const bf16x8*)(ks + row * 128 + ((df * 4 + lrow) ^ sw) * 8);
                s = __builtin_amdgcn_mfma_f32_16x16x32_bf16(aq[df], kf, s, 0, 0, 0);
            }
            S[sub] = s;
        }

        float p[4][4], tmax[4];
        #pragma unroll
        for (int r = 0; r < 4; ++r) tmax[r] = -__builtin_inff();
        #pragma unroll
        for (int sub = 0; sub < 4; ++sub) {
            const int kj = j0 + sub * 16 + lcol;
            #pragma unroll
            for (int r = 0; r < 4; ++r) {
                const int qi = q0 + lrow * 4 + r;
                float v = S[sub][r] * scale;
                if (qi < 60 && kj < 60) v += abias[(h * 15 + (qi >> 2)) * 15 + (kj >> 2)];
                v = ((kj <= qi) && ((kj & 63) != 63)) ? v : -__builtin_inff();
                p[sub][r] = v;
                tmax[r] = fmaxf(tmax[r], v);
            }
        }
        #pragma unroll
        for (int off = 1; off < 16; off <<= 1)
            #pragma unroll
            for (int r = 0; r < 4; ++r) tmax[r] = fmaxf(tmax[r], __shfl_xor(tmax[r], off));
        float alpha[4], rsum[4];
        #pragma unroll
        for (int r = 0; r < 4; ++r) {
            float mnew = fmaxf(mrun[r], tmax[r]);
            alpha[r] = __expf(mrun[r] - mnew);
            mrun[r] = mnew;
            float acc = 0.f;
            #pragma unroll
            for (int sub = 0; sub < 4; ++sub) { p[sub][r] = __expf(p[sub][r] - mnew); acc += p[sub][r]; }
            rsum[r] = acc;
        }
        #pragma unroll
        for (int off = 1; off < 16; off <<= 1)
            #pragma unroll
            for (int r = 0; r < 4; ++r) rsum[r] += __shfl_xor(rsum[r], off);
        #pragma unroll
        for (int r = 0; r < 4; ++r) lrun[r] = lrun[r] * alpha[r] + rsum[r];
        #pragma unroll
        for (int i = 0; i < 8; ++i)
            #pragma unroll
            for (int r = 0; r < 4; ++r) o[i][r] *= alpha[r];

        #pragma unroll
        for (int sub = 0; sub < 4; ++sub)
            #pragma unroll
            for (int r = 0; r < 4; ++r)
                psw[(lrow * 4 + r) * 72 + sub * 16 + lcol] = f2b(p[sub][r]);

        #pragma unroll
        for (int kt = 0; kt < 2; ++kt) {
            bf16x8 pa = *(const bf16x8*)(psw + lcol * 72 + kt * 32 + lrow * 8);
            #pragma unroll
            for (int of = 0; of < 8; ++of) {
                const int d = of * 16 + lcol;
                bf16x8 vf = *(const bf16x8*)(vt + d * 64 + ((kt * 32 + lrow * 8) ^ ((d & 7) << 3)));
                o[of] = __builtin_amdgcn_mfma_f32_16x16x32_bf16(pa, vf, o[of], 0, 0, 0);
            }
        }

        if (more) v_write(nxt, vn);
    }

    u16* yp = yb + (size_t)b * 1024 * 1024 + h * 128;
    #pragma unroll
    for (int of = 0; of < 8; ++of)
        #pragma unroll
        for (int r = 0; r < 4; ++r) {
            int row = q0 + lrow * 4 + r;
            yp[(size_t)row * 1024 + of * 16 + lcol] = f2b(o[of][r] / lrun[r]);
        }
}

// ---------------------------------------------------------------- head (MFMA)
__global__ __launch_bounds__(256) void k_head(const u16* __restrict__ hln,
                                              const u16* __restrict__ hw16,
                                              float* __restrict__ out) {
    const int e = blockIdx.x, bq = blockIdx.y;
    const int lane = threadIdx.x & 63, wave = threadIdx.x >> 6;
    const int lcol = lane & 15, lrow = lane >> 4;

    const u16* ap = hln + ((size_t)bq * 1024 + lcol * 64 + e) * 1024 + lrow * 8;
    const int nt0 = wave, nt1 = wave + 4;
    const int oo0 = nt0 * 16 + lcol, oo1 = nt1 * 16 + lcol;
    const bool v0 = oo0 < 101;
    const bool has1 = nt1 < 7;
    const bool v1 = has1 && (oo1 < 101);
    const u16* bp0 = hw16 + ((size_t)e * 101 + (v0 ? oo0 : 0)) * 1024 + lrow * 8;
    const u16* bp1 = hw16 + ((size_t)e * 101 + (v1 ? oo1 : 0)) * 1024 + lrow * 8;

    f32x4 acc0 = {}, acc1 = {};
    #pragma unroll 4
    for (int kt = 0; kt < 32; ++kt) {
        bf16x8 af = *(const bf16x8*)(ap + kt * 32);
        bf16x8 b0 = {};
        if (v0) b0 = *(const bf16x8*)(bp0 + kt * 32);
        acc0 = __builtin_amdgcn_mfma_f32_16x16x32_bf16(af, b0, acc0, 0, 0, 0);
        if (has1) {
            bf16x8 b1 = {};
            if (v1) b1 = *(const bf16x8*)(bp1 + kt * 32);
            acc1 = __builtin_amdgcn_mfma_f32_16x16x32_bf16(af, b1, acc1, 0, 0, 0);
        }
    }

    #pragma unroll
    for (int r = 0; r < 4; ++r) {
        size_t row = (size_t)bq * 1024 + (lrow * 4 + r) * 64 + e;
        if (v0) out[row * 101 + oo0] = acc0[r];
        if (v1) out[row * 101 + oo1] = acc1[r];
    }
}

// ---------------------------------------------------------------- launch
extern "C" void kernel_launch(void* const* d_in, const int* in_sizes, int n_in,
                              void* d_out, int out_size, void* d_ws, size_t ws_size,
                              hipStream_t stream) {
    (void)in_sizes; (void)n_in; (void)out_size; (void)ws_size;
    const float* x     = (const float*)d_in[0];
    const float* abias = (const float*)d_in[1];
    const float* pos   = (const float*)d_in[2];
    const float* Wq    = (const float*)d_in[3];
    const float* bq    = (const float*)d_in[4];
    const float* Wk    = (const float*)d_in[5];
    const float* bk    = (const float*)d_in[6];
    const float* Wv    = (const float*)d_in[7];
    const float* bv    = (const float*)d_in[8];
    const float* Wp    = (const float*)d_in[9];
    const float* bp    = (const float*)d_in[10];
    const float* ln1g  = (const float*)d_in[11];
    const float* ln1b  = (const float*)d_in[12];
    const float* ln2g  = (const float*)d_in[13];
    const float* ln2b  = (const float*)d_in[14];
    const float* w1    = (const float*)d_in[15];
    const float* b1    = (const float*)d_in[16];
    const float* w2    = (const float*)d_in[17];
    const float* b2    = (const float*)d_in[18];
    const float* lnfg  = (const float*)d_in[19];
    const float* lnfb  = (const float*)d_in[20];
    const float* hw    = (const float*)d_in[21];
    float* out = (float*)d_out;

    char* ws = (char*)d_ws;
    size_t off = 0;
    auto alloc = [&](size_t bytes) { void* p = ws + off; off += (bytes + 255) & ~(size_t)255; return p; };
    float* H    = (float*)alloc(4096ull * 1024 * 4);
    u16* ABF    = (u16*)alloc(4096ull * 1024 * 2);
    char* R     = (char*)alloc(4096ull * 4096 * 2);      // QKV(24MB)+YB(8MB) / MB(32MB) aliased
    u16* QKV    = (u16*)R;
    u16* YB     = (u16*)(R + 4096ull * 3072 * 2);
    u16* MB     = (u16*)R;
    u16* WQKV   = (u16*)alloc(4ull * 3072 * 1024 * 2);
    u16* WPT    = (u16*)alloc(4ull * 1024 * 1024 * 2);
    u16* W1T    = (u16*)alloc(4ull * 1024 * 4096 * 2);
    u16* W2T    = (u16*)alloc(4ull * 4096 * 1024 * 2);
    u16* HW16   = (u16*)alloc(64ull * 101 * 1024 * 2);
    float* BQKV = (float*)alloc(4ull * 3072 * 4);

    dim3 blk(256);
    const size_t QS = 3072ull * 1024;
    k_transcvt<<<dim3(32, 32, 4), blk, 0, stream>>>(Wq, WQKV,                    1024, 1024, QS);
    k_transcvt<<<dim3(32, 32, 4), blk, 0, stream>>>(Wk, WQKV + 1024ull * 1024,   1024, 1024, QS);
    k_transcvt<<<dim3(32, 32, 4), blk, 0, stream>>>(Wv, WQKV + 2048ull * 1024,   1024, 1024, QS);
    k_transcvt<<<dim3(32, 32, 4), blk, 0, stream>>>(Wp, WPT, 1024, 1024, 1048576);
    k_transcvt<<<dim3(128, 32, 4), blk, 0, stream>>>(w1, W1T, 1024, 4096, 4194304);
    k_transcvt<<<dim3(32, 128, 4), blk, 0, stream>>>(w2, W2T, 4096, 1024, 4194304);
    k_cvt<<<dim3(64 * 101 * 1024 / 4 / 256), blk, 0, stream>>>(hw, HW16, 64 * 101 * 1024 / 4);
    k_packb<<<dim3(4), blk, 0, stream>>>(bq, bk, bv, BQKV);
    k_addpos<<<dim3(4096), blk, 0, stream>>>(x, pos, H);

    for (int l = 0; l < 4; ++l) {
        k_ln<<<dim3(4096), blk, 0, stream>>>(H, ln1g + l * 1024, ln1b + l * 1024, ABF);
        k_g128<0><<<dim3(12, 32), dim3(512), 0, stream>>>(ABF, WQKV + (size_t)l * QS, BQKV + l * 3072, QKV, 4096, 3072, 1024);
        k_attn<<<dim3(512), blk, 0, stream>>>(QKV, abias, YB);
        k_gemmr<<<dim3(8, 64), blk, 0, stream>>>(YB, WPT + (size_t)l * 1048576, bp + l * 1024, H, 4096, 1024, 1024);
        k_ln<<<dim3(4096), blk, 0, stream>>>(H, ln2g + l * 1024, ln2b + l * 1024, ABF);
        k_g128<1><<<dim3(16, 32), dim3(512), 0, stream>>>(ABF, W1T + (size_t)l * 4194304, b1 + l * 4096, MB, 4096, 4096, 1024);
        k_gemmr<<<dim3(8, 64), blk, 0, stream>>>(MB, W2T + (size_t)l * 4194304, b2 + l * 1024, H, 4096, 1024, 4096);
    }
    k_ln<<<dim3(4096), blk, 0, stream>>>(H, lnfg, lnfb, ABF);
    k_head<<<dim3(64, 4), blk, 0, stream>>>(ABF, HW16, out);
}

// Round 10
// 996.153 us; speedup vs baseline: 1.0556x; 1.0556x over previous
//
#include <hip/hip_runtime.h>
#include <cstdint>

#define DEV __device__ __forceinline__

typedef unsigned short u16;
typedef __attribute__((ext_vector_type(8))) short bf16x8;   // 8 bf16 = 4 VGPRs (MFMA A/B frag)
typedef __attribute__((ext_vector_type(4))) unsigned short u16x4;
typedef __attribute__((ext_vector_type(4))) float f32x4;    // MFMA C/D frag

typedef __attribute__((address_space(1))) const void GV;
typedef __attribute__((address_space(3))) void LV;

DEV float b2f(u16 u) { uint32_t i = ((uint32_t)u) << 16; return __builtin_bit_cast(float, i); }
DEV u16 f2b(float f) {
    uint32_t i = __builtin_bit_cast(uint32_t, f);
    return (u16)((i + 0x7fffu + ((i >> 16) & 1u)) >> 16);   // RNE
}
DEV void load_lds16(const void* g, void* l) {
    // dest = wave-uniform LDS base + lane*16B; src is per-lane global, 16B contiguous
    __builtin_amdgcn_global_load_lds((GV*)g, (LV*)l, 16, 0, 0);
}

// ---------------------------------------------------------------- elementwise
__global__ __launch_bounds__(256) void k_addpos(const float* __restrict__ x,
                                                const float* __restrict__ pos,
                                                float* __restrict__ h) {
    size_t i = (size_t)blockIdx.x * 256 + threadIdx.x;
    f32x4 a = *(const f32x4*)(x + i * 4);
    f32x4 p = *(const f32x4*)(pos + ((i * 4) & 1048575));
    a += p;
    *(f32x4*)(h + i * 4) = a;
}

// fp32 [K][N] -> bf16 [N][K] (transposed); in z-stride K*N, out z-stride ozs
__global__ __launch_bounds__(256) void k_transcvt(const float* __restrict__ W,
                                                  u16* __restrict__ WT, int K, int N,
                                                  size_t ozs) {
    __shared__ float t[32][33];
    size_t zin = (size_t)blockIdx.z * K * N, zout = (size_t)blockIdx.z * ozs;
    int n0 = blockIdx.x * 32, k0 = blockIdx.y * 32;
    int r = threadIdx.x >> 3, c = (threadIdx.x & 7) << 2;
    f32x4 v = *(const f32x4*)(W + zin + (size_t)(k0 + r) * N + n0 + c);
    t[r][c] = v[0]; t[r][c + 1] = v[1]; t[r][c + 2] = v[2]; t[r][c + 3] = v[3];
    __syncthreads();
    u16x4 o;
    o[0] = f2b(t[c][r]); o[1] = f2b(t[c + 1][r]); o[2] = f2b(t[c + 2][r]); o[3] = f2b(t[c + 3][r]);
    *(u16x4*)(WT + zout + (size_t)(n0 + r) * K + k0 + c) = o;
}

// fp32 -> bf16 flat convert (head weights)
__global__ __launch_bounds__(256) void k_cvt(const float* __restrict__ in,
                                             u16* __restrict__ out, int n4) {
    int i = blockIdx.x * 256 + threadIdx.x;
    if (i < n4) {
        f32x4 v = *(const f32x4*)(in + (size_t)i * 4);
        u16x4 o; o[0] = f2b(v[0]); o[1] = f2b(v[1]); o[2] = f2b(v[2]); o[3] = f2b(v[3]);
        *(u16x4*)(out + (size_t)i * 4) = o;
    }
}

// pack per-layer q/k/v biases into [L][3072]
__global__ __launch_bounds__(256) void k_packb(const float* __restrict__ bq,
                                               const float* __restrict__ bk,
                                               const float* __restrict__ bv,
                                               float* __restrict__ bqkv) {
    int l = blockIdx.x;
    for (int i = threadIdx.x; i < 1024; i += 256) {
        bqkv[l * 3072 + i]        = bq[l * 1024 + i];
        bqkv[l * 3072 + 1024 + i] = bk[l * 1024 + i];
        bqkv[l * 3072 + 2048 + i] = bv[l * 1024 + i];
    }
}

// ---------------------------------------------------------------- layernorm
__global__ __launch_bounds__(256) void k_ln(const float* __restrict__ in,
                                            const float* __restrict__ g,
                                            const float* __restrict__ bta,
                                            u16* __restrict__ out) {
    int row = blockIdx.x, tid = threadIdx.x;
    const float* rp = in + (size_t)row * 1024;
    f32x4 v = *(const f32x4*)(rp + tid * 4);
    float s = v[0] + v[1] + v[2] + v[3];
    float ss = v[0] * v[0] + v[1] * v[1] + v[2] * v[2] + v[3] * v[3];
    #pragma unroll
    for (int off = 32; off; off >>= 1) { s += __shfl_down(s, off); ss += __shfl_down(ss, off); }
    __shared__ float rs[4], rss[4];
    int wave = tid >> 6, lane = tid & 63;
    if (!lane) { rs[wave] = s; rss[wave] = ss; }
    __syncthreads();
    float ts = rs[0] + rs[1] + rs[2] + rs[3];
    float tss = rss[0] + rss[1] + rss[2] + rss[3];
    float mean = ts * (1.0f / 1024.0f);
    float var = tss * (1.0f / 1024.0f) - mean * mean;
    float rstd = rsqrtf(var + 1e-5f);
    f32x4 gv = *(const f32x4*)(g + tid * 4);
    f32x4 bv = *(const f32x4*)(bta + tid * 4);
    u16x4 o;
    #pragma unroll
    for (int j = 0; j < 4; ++j) o[j] = f2b((v[j] - mean) * rstd * gv[j] + bv[j]);
    *(u16x4*)(out + (size_t)row * 1024 + tid * 4) = o;
}

// ---------------------------------------------------------------- GEMM 64x64 (residual add)
// H[M][N] += A[M][K] @ BT[N][K]^T + bias. BM=BN=64 BK=64, 4 waves (2x2),
// wave-tile 32x32. Simple dbuf + __syncthreads (proven structure); small tile
// -> grid (N/64, M/64) = 1024 blocks = 4 blocks/CU co-resident, which is the
// latency-hiding mechanism (round-9 counted-vmcnt pipeline at 2/CU regressed).
// XOR chunk swizzle both-sides (rows are 128B: 8x16B slots ^ row&7).
__global__ __launch_bounds__(256) void k_gemmr(const u16* __restrict__ A,
                                               const u16* __restrict__ BT,
                                               const float* __restrict__ bias,
                                               float* __restrict__ H,
                                               int M, int N, int K) {
    __shared__ __align__(16) u16 As[2][64 * 64];     // [m][k] swizzled
    __shared__ __align__(16) u16 Bs[2][64 * 64];     // [n][k] swizzled
    const int tid = threadIdx.x, lane = tid & 63, wave = tid >> 6;
    const int wy = wave >> 1, wx = wave & 1;
    const int lcol = lane & 15, lrow = lane >> 4;

    const int nbx = gridDim.x, nwg = nbx * gridDim.y;
    int id = blockIdx.y * nbx + blockIdx.x;
    int q = nwg >> 3, r = nwg & 7;
    int xcd = id & 7, pos = id >> 3;
    int nid = (xcd < r ? xcd * (q + 1) : r * (q + 1) + (xcd - r) * q) + pos;
    const int m0 = (nid / nbx) * 64, n0 = (nid % nbx) * 64;
    const int NT = K >> 6;

    f32x4 acc[2][2] = {};

    auto stage = [&](int buf, int kt) {              // 4 global_load_lds per thread
        int k0 = kt << 6;
        #pragma unroll
        for (int it = 0; it < 2; ++it) {             // A: 512 chunks (64 rows x 8 slots)
            int c = it * 256 + tid;
            int row = c >> 3, s = (c & 7) ^ (row & 7);
            load_lds16(A + (size_t)(m0 + row) * K + k0 + s * 8,
                       &As[buf][(it * 256 + wave * 64) * 8]);
        }
        #pragma unroll
        for (int it = 0; it < 2; ++it) {             // B: 512 chunks
            int c = it * 256 + tid;
            int row = c >> 3, s = (c & 7) ^ (row & 7);
            load_lds16(BT + (size_t)(n0 + row) * K + k0 + s * 8,
                       &Bs[buf][(it * 256 + wave * 64) * 8]);
        }
    };

    stage(0, 0);
    for (int kt = 0; kt < NT; ++kt) {
        __syncthreads();
        if (kt + 1 < NT) stage((kt + 1) & 1, kt + 1);
        const u16* ab = As[kt & 1];
        const u16* bb = Bs[kt & 1];
        #pragma unroll
        for (int kc = 0; kc < 2; ++kc) {
            bf16x8 af[2], bfr[2];
            #pragma unroll
            for (int mi = 0; mi < 2; ++mi) {
                int mrow = wy * 32 + mi * 16 + lcol;
                int s = (kc * 4 + lrow) ^ (mrow & 7);
                af[mi] = *(const bf16x8*)(ab + mrow * 64 + s * 8);
            }
            #pragma unroll
            for (int ni = 0; ni < 2; ++ni) {
                int nrow = wx * 32 + ni * 16 + lcol;
                int s = (kc * 4 + lrow) ^ (nrow & 7);
                bfr[ni] = *(const bf16x8*)(bb + nrow * 64 + s * 8);
            }
            #pragma unroll
            for (int mi = 0; mi < 2; ++mi)
                #pragma unroll
                for (int ni = 0; ni < 2; ++ni)
                    acc[mi][ni] = __builtin_amdgcn_mfma_f32_16x16x32_bf16(af[mi], bfr[ni], acc[mi][ni], 0, 0, 0);
        }
    }

    #pragma unroll
    for (int mi = 0; mi < 2; ++mi) {
        #pragma unroll
        for (int ni = 0; ni < 2; ++ni) {
            int col = n0 + wx * 32 + ni * 16 + lcol;
            float bcol = bias[col];
            #pragma unroll
            for (int r2 = 0; r2 < 4; ++r2) {
                int row = m0 + wy * 32 + mi * 16 + lrow * 4 + r2;
                float* o = H + (size_t)row * N + col;
                *o = *o + acc[mi][ni][r2] + bcol;
            }
        }
    }
}

// ---------------------------------------------------------------- GEMM 128x256
// 512 threads, 8 waves (2 m x 4 n), wave-tile 64x64, BK=32, dbuf (48 KB LDS ->
// 2+ blocks/CU co-resident hide 2-phase drains). XOR swizzle f(row)=(row>>1)&3
// both-sides. Bijective XCD block swizzle. EPI: 0 = bf16, 1 = gelu.
template <int EPI>
__global__ __launch_bounds__(512) void k_g128(const u16* __restrict__ A,
                                              const u16* __restrict__ BT,
                                              const float* __restrict__ bias,
                                              u16* __restrict__ Cout,
                                              int M, int N, int K) {
    __shared__ __align__(16) u16 As[2][4096];   // [128 m][32 k]
    __shared__ __align__(16) u16 Bs[2][8192];   // [256 n][32 k]
    const int tid = threadIdx.x, lane = tid & 63, wave = tid >> 6;
    const int wy = wave >> 2, wx = wave & 3;
    const int lcol = lane & 15, lrow = lane >> 4;

    const int nbx = gridDim.x, nwg = nbx * gridDim.y;
    int id = blockIdx.y * nbx + blockIdx.x;
    int q = nwg >> 3, r = nwg & 7;
    int xcd = id & 7, pos = id >> 3;
    int nid = (xcd < r ? xcd * (q + 1) : r * (q + 1) + (xcd - r) * q) + pos;
    const int m0 = (nid / nbx) * 128, n0 = (nid % nbx) * 256;
    const int NT = K >> 5;

    f32x4 acc[4][4] = {};

    auto stage = [&](int buf, int kt) {
        int k0 = kt << 5;
        {   // A: 512 chunks (128 rows x 4 slots), 1/thread
            int c = tid;
            int row = c >> 2, s = (c & 3) ^ ((row >> 1) & 3);
            load_lds16(A + (size_t)(m0 + row) * K + k0 + s * 8,
                       &As[buf][(wave * 64) * 8]);
        }
        #pragma unroll
        for (int it = 0; it < 2; ++it) {   // B: 1024 chunks (256 rows x 4 slots)
            int c = it * 512 + tid;
            int row = c >> 2, s = (c & 3) ^ ((row >> 1) & 3);
            load_lds16(BT + (size_t)(n0 + row) * K + k0 + s * 8,
                       &Bs[buf][(it * 512 + wave * 64) * 8]);
        }
    };

    stage(0, 0);
    for (int kt = 0; kt < NT; ++kt) {
        __syncthreads();
        if (kt + 1 < NT) stage((kt + 1) & 1, kt + 1);
        const u16* ab = As[kt & 1];
        const u16* bb = Bs[kt & 1];
        bf16x8 bfr[4];
        #pragma unroll
        for (int ni = 0; ni < 4; ++ni) {
            int nrow = wx * 64 + ni * 16 + lcol;
            bfr[ni] = *(const bf16x8*)(bb + nrow * 32 + ((lrow ^ ((nrow >> 1) & 3)) * 8));
        }
        #pragma unroll
        for (int mi = 0; mi < 4; ++mi) {
            int mrow = wy * 64 + mi * 16 + lcol;
            bf16x8 af = *(const bf16x8*)(ab + mrow * 32 + ((lrow ^ ((mrow >> 1) & 3)) * 8));
            #pragma unroll
            for (int ni = 0; ni < 4; ++ni)
                acc[mi][ni] = __builtin_amdgcn_mfma_f32_16x16x32_bf16(af, bfr[ni], acc[mi][ni], 0, 0, 0);
        }
    }

    #pragma unroll
    for (int mi = 0; mi < 4; ++mi) {
        #pragma unroll
        for (int ni = 0; ni < 4; ++ni) {
            int col = n0 + wx * 64 + ni * 16 + lcol;
            float bcol = bias[col];
            #pragma unroll
            for (int r2 = 0; r2 < 4; ++r2) {
                int row = m0 + wy * 64 + mi * 16 + lrow * 4 + r2;
                float val = acc[mi][ni][r2] + bcol;
                if constexpr (EPI == 1)
                    val = 0.5f * val * (1.0f + erff(val * 0.70710678118654752f));
                Cout[(size_t)row * N + col] = f2b(val);
            }
        }
    }
}

// ---------------------------------------------------------------- attention
// QKV fused input [4096][3072] bf16 (q|k|v per 1024 cols), head h at +h*128.
__global__ __launch_bounds__(256) void k_attn(const u16* __restrict__ qkv,
                                              const float* __restrict__ abias,
                                              u16* __restrict__ yb) {
    __shared__ __align__(16) u16 Ks[2][64 * 128];
    __shared__ __align__(16) u16 Vt[2][128 * 64];
    __shared__ __align__(16) u16 Ps[4][16 * 72];

    const int idx = blockIdx.x;
    const int half = idx >> 8, u = idx & 255;
    const int qt = half ? (15 - (u & 15)) : (u & 15);
    const int h = (u >> 4) & 7;
    const int b = (u >> 7) + half * 2;

    const int tid = threadIdx.x, wave = tid >> 6, lane = tid & 63;
    const int lcol = lane & 15, lrow = lane >> 4;
    const int q0 = qt * 64 + wave * 16;
    const size_t base = (size_t)b * 1024 * 3072 + h * 128;
    const u16* qp = qkv + base;
    const u16* kp = qkv + base + 1024;
    const u16* vp = qkv + base + 2048;
    u16* psw = Ps[wave];
    const int j4 = tid & 15, d8 = tid >> 4;

    bf16x8 aq[4];
    #pragma unroll
    for (int df = 0; df < 4; ++df)
        aq[df] = *(const bf16x8*)(qp + (size_t)(q0 + lcol) * 3072 + df * 32 + lrow * 8);

    f32x4 o[8];
    #pragma unroll
    for (int i = 0; i < 8; ++i) o[i] = f32x4{0.f, 0.f, 0.f, 0.f};
    float mrun[4], lrun[4];
    #pragma unroll
    for (int r = 0; r < 4; ++r) { mrun[r] = -__builtin_inff(); lrun[r] = 0.f; }

    const float scale = 0.08838834764831845f;
    const int nt = qt + 1;

    auto k_issue = [&](int buf, int t) {
        const int j0 = t * 64;
        #pragma unroll
        for (int it = 0; it < 4; ++it) {
            int c = it * 256 + wave * 64 + lane;
            int row = c >> 4, slot = c & 15;
            int sslot = slot ^ (row & 7);
            load_lds16(kp + (size_t)(j0 + row) * 3072 + sslot * 8,
                       &Ks[buf][(it * 256 + wave * 64) * 8]);
        }
    };
    auto v_issue = [&](int t, bf16x8* vr) {
        const int j0 = t * 64;
        #pragma unroll
        for (int r = 0; r < 4; ++r)
            vr[r] = *(const bf16x8*)(vp + (size_t)(j0 + j4 * 4 + r) * 3072 + d8 * 8);
    };
    auto v_write = [&](int buf, const bf16x8* vr) {
        #pragma unroll
        for (int i = 0; i < 8; ++i) {
            int d = d8 * 8 + i;
            u16x4 w;
            w[0] = (u16)vr[0][i]; w[1] = (u16)vr[1][i]; w[2] = (u16)vr[2][i]; w[3] = (u16)vr[3][i];
            *(u16x4*)(&Vt[buf][d * 64 + ((j4 * 4) ^ (i << 3))]) = w;
        }
    };

    bf16x8 v0r[4];
    k_issue(0, 0);
    v_issue(0, v0r);
    v_write(0, v0r);

    for (int t = 0; t < nt; ++t) {
        __syncthreads();
        const int cur = t & 1, nxt = cur ^ 1;
        const bool more = (t + 1 < nt);
        bf16x8 vn[4];
        if (more) { k_issue(nxt, t + 1); v_issue(t + 1, vn); }

        const u16* ks = Ks[cur];
        const u16* vt = Vt[cur];
        const int j0 = t * 64;

        f32x4 S[4];
        #pragma unroll
        for (int sub = 0; sub < 4; ++sub) {
            const int row = sub * 16 + lcol;
            const int sw = row & 7;
            f32x4 s = {};
            #pragma unroll
            for (int df = 0; df < 4; ++df) {
                bf16x8 kf = *(const bf16x8*)(ks + row * 128 + ((df * 4 + lrow) ^ sw) * 8);
                s = __builtin_amdgcn_mfma_f32_16x16x32_bf16(aq[df], kf, s, 0, 0, 0);
            }
            S[sub] = s;
        }

        float p[4][4], tmax[4];
        #pragma unroll
        for (int r = 0; r < 4; ++r) tmax[r] = -__builtin_inff();
        #pragma unroll
        for (int sub = 0; sub < 4; ++sub) {
            const int kj = j0 + sub * 16 + lcol;
            #pragma unroll
            for (int r = 0; r < 4; ++r) {
                const int qi = q0 + lrow * 4 + r;
                float v = S[sub][r] * scale;
                if (qi < 60 && kj < 60) v += abias[(h * 15 + (qi >> 2)) * 15 + (kj >> 2)];
                v = ((kj <= qi) && ((kj & 63) != 63)) ? v : -__builtin_inff();
                p[sub][r] = v;
                tmax[r] = fmaxf(tmax[r], v);
            }
        }
        #pragma unroll
        for (int off = 1; off < 16; off <<= 1)
            #pragma unroll
            for (int r = 0; r < 4; ++r) tmax[r] = fmaxf(tmax[r], __shfl_xor(tmax[r], off));
        float alpha[4], rsum[4];
        #pragma unroll
        for (int r = 0; r < 4; ++r) {
            float mnew = fmaxf(mrun[r], tmax[r]);
            alpha[r] = __expf(mrun[r] - mnew);
            mrun[r] = mnew;
            float acc = 0.f;
            #pragma unroll
            for (int sub = 0; sub < 4; ++sub) { p[sub][r] = __expf(p[sub][r] - mnew); acc += p[sub][r]; }
            rsum[r] = acc;
        }
        #pragma unroll
        for (int off = 1; off < 16; off <<= 1)
            #pragma unroll
            for (int r = 0; r < 4; ++r) rsum[r] += __shfl_xor(rsum[r], off);
        #pragma unroll
        for (int r = 0; r < 4; ++r) lrun[r] = lrun[r] * alpha[r] + rsum[r];
        #pragma unroll
        for (int i = 0; i < 8; ++i)
            #pragma unroll
            for (int r = 0; r < 4; ++r) o[i][r] *= alpha[r];

        #pragma unroll
        for (int sub = 0; sub < 4; ++sub)
            #pragma unroll
            for (int r = 0; r < 4; ++r)
                psw[(lrow * 4 + r) * 72 + sub * 16 + lcol] = f2b(p[sub][r]);

        #pragma unroll
        for (int kt = 0; kt < 2; ++kt) {
            bf16x8 pa = *(const bf16x8*)(psw + lcol * 72 + kt * 32 + lrow * 8);
            #pragma unroll
            for (int of = 0; of < 8; ++of) {
                const int d = of * 16 + lcol;
                bf16x8 vf = *(const bf16x8*)(vt + d * 64 + ((kt * 32 + lrow * 8) ^ ((d & 7) << 3)));
                o[of] = __builtin_amdgcn_mfma_f32_16x16x32_bf16(pa, vf, o[of], 0, 0, 0);
            }
        }

        if (more) v_write(nxt, vn);
    }

    u16* yp = yb + (size_t)b * 1024 * 1024 + h * 128;
    #pragma unroll
    for (int of = 0; of < 8; ++of)
        #pragma unroll
        for (int r = 0; r < 4; ++r) {
            int row = q0 + lrow * 4 + r;
            yp[(size_t)row * 1024 + of * 16 + lcol] = f2b(o[of][r] / lrun[r]);
        }
}

// ---------------------------------------------------------------- head (MFMA)
__global__ __launch_bounds__(256) void k_head(const u16* __restrict__ hln,
                                              const u16* __restrict__ hw16,
                                              float* __restrict__ out) {
    const int e = blockIdx.x, bq = blockIdx.y;
    const int lane = threadIdx.x & 63, wave = threadIdx.x >> 6;
    const int lcol = lane & 15, lrow = lane >> 4;

    const u16* ap = hln + ((size_t)bq * 1024 + lcol * 64 + e) * 1024 + lrow * 8;
    const int nt0 = wave, nt1 = wave + 4;
    const int oo0 = nt0 * 16 + lcol, oo1 = nt1 * 16 + lcol;
    const bool v0 = oo0 < 101;
    const bool has1 = nt1 < 7;
    const bool v1 = has1 && (oo1 < 101);
    const u16* bp0 = hw16 + ((size_t)e * 101 + (v0 ? oo0 : 0)) * 1024 + lrow * 8;
    const u16* bp1 = hw16 + ((size_t)e * 101 + (v1 ? oo1 : 0)) * 1024 + lrow * 8;

    f32x4 acc0 = {}, acc1 = {};
    #pragma unroll 4
    for (int kt = 0; kt < 32; ++kt) {
        bf16x8 af = *(const bf16x8*)(ap + kt * 32);
        bf16x8 b0 = {};
        if (v0) b0 = *(const bf16x8*)(bp0 + kt * 32);
        acc0 = __builtin_amdgcn_mfma_f32_16x16x32_bf16(af, b0, acc0, 0, 0, 0);
        if (has1) {
            bf16x8 b1 = {};
            if (v1) b1 = *(const bf16x8*)(bp1 + kt * 32);
            acc1 = __builtin_amdgcn_mfma_f32_16x16x32_bf16(af, b1, acc1, 0, 0, 0);
        }
    }

    #pragma unroll
    for (int r = 0; r < 4; ++r) {
        size_t row = (size_t)bq * 1024 + (lrow * 4 + r) * 64 + e;
        if (v0) out[row * 101 + oo0] = acc0[r];
        if (v1) out[row * 101 + oo1] = acc1[r];
    }
}

// ---------------------------------------------------------------- launch
extern "C" void kernel_launch(void* const* d_in, const int* in_sizes, int n_in,
                              void* d_out, int out_size, void* d_ws, size_t ws_size,
                              hipStream_t stream) {
    (void)in_sizes; (void)n_in; (void)out_size; (void)ws_size;
    const float* x     = (const float*)d_in[0];
    const float* abias = (const float*)d_in[1];
    const float* pos   = (const float*)d_in[2];
    const float* Wq    = (const float*)d_in[3];
    const float* bq    = (const float*)d_in[4];
    const float* Wk    = (const float*)d_in[5];
    const float* bk    = (const float*)d_in[6];
    const float* Wv    = (const float*)d_in[7];
    const float* bv    = (const float*)d_in[8];
    const float* Wp    = (const float*)d_in[9];
    const float* bp    = (const float*)d_in[10];
    const float* ln1g  = (const float*)d_in[11];
    const float* ln1b  = (const float*)d_in[12];
    const float* ln2g  = (const float*)d_in[13];
    const float* ln2b  = (const float*)d_in[14];
    const float* w1    = (const float*)d_in[15];
    const float* b1    = (const float*)d_in[16];
    const float* w2    = (const float*)d_in[17];
    const float* b2    = (const float*)d_in[18];
    const float* lnfg  = (const float*)d_in[19];
    const float* lnfb  = (const float*)d_in[20];
    const float* hw    = (const float*)d_in[21];
    float* out = (float*)d_out;

    char* ws = (char*)d_ws;
    size_t off = 0;
    auto alloc = [&](size_t bytes) { void* p = ws + off; off += (bytes + 255) & ~(size_t)255; return p; };
    float* H    = (float*)alloc(4096ull * 1024 * 4);
    u16* ABF    = (u16*)alloc(4096ull * 1024 * 2);
    char* R     = (char*)alloc(4096ull * 4096 * 2);      // QKV(24MB)+YB(8MB) / MB(32MB) aliased
    u16* QKV    = (u16*)R;
    u16* YB     = (u16*)(R + 4096ull * 3072 * 2);
    u16* MB     = (u16*)R;
    u16* WQKV   = (u16*)alloc(4ull * 3072 * 1024 * 2);
    u16* WPT    = (u16*)alloc(4ull * 1024 * 1024 * 2);
    u16* W1T    = (u16*)alloc(4ull * 1024 * 4096 * 2);
    u16* W2T    = (u16*)alloc(4ull * 4096 * 1024 * 2);
    u16* HW16   = (u16*)alloc(64ull * 101 * 1024 * 2);
    float* BQKV = (float*)alloc(4ull * 3072 * 4);

    dim3 blk(256);
    const size_t QS = 3072ull * 1024;
    k_transcvt<<<dim3(32, 32, 4), blk, 0, stream>>>(Wq, WQKV,                    1024, 1024, QS);
    k_transcvt<<<dim3(32, 32, 4), blk, 0, stream>>>(Wk, WQKV + 1024ull * 1024,   1024, 1024, QS);
    k_transcvt<<<dim3(32, 32, 4), blk, 0, stream>>>(Wv, WQKV + 2048ull * 1024,   1024, 1024, QS);
    k_transcvt<<<dim3(32, 32, 4), blk, 0, stream>>>(Wp, WPT, 1024, 1024, 1048576);
    k_transcvt<<<dim3(128, 32, 4), blk, 0, stream>>>(w1, W1T, 1024, 4096, 4194304);
    k_transcvt<<<dim3(32, 128, 4), blk, 0, stream>>>(w2, W2T, 4096, 1024, 4194304);
    k_cvt<<<dim3(64 * 101 * 1024 / 4 / 256), blk, 0, stream>>>(hw, HW16, 64 * 101 * 1024 / 4);
    k_packb<<<dim3(4), blk, 0, stream>>>(bq, bk, bv, BQKV);
    k_addpos<<<dim3(4096), blk, 0, stream>>>(x, pos, H);

    for (int l = 0; l < 4; ++l) {
        k_ln<<<dim3(4096), blk, 0, stream>>>(H, ln1g + l * 1024, ln1b + l * 1024, ABF);
        k_g128<0><<<dim3(12, 32), dim3(512), 0, stream>>>(ABF, WQKV + (size_t)l * QS, BQKV + l * 3072, QKV, 4096, 3072, 1024);
        k_attn<<<dim3(512), blk, 0, stream>>>(QKV, abias, YB);
        k_gemmr<<<dim3(16, 64), blk, 0, stream>>>(YB, WPT + (size_t)l * 1048576, bp + l * 1024, H, 4096, 1024, 1024);
        k_ln<<<dim3(4096), blk, 0, stream>>>(H, ln2g + l * 1024, ln2b + l * 1024, ABF);
        k_g128<1><<<dim3(16, 32), dim3(512), 0, stream>>>(ABF, W1T + (size_t)l * 4194304, b1 + l * 4096, MB, 4096, 4096, 1024);
        k_gemmr<<<dim3(16, 64), blk, 0, stream>>>(MB, W2T + (size_t)l * 4194304, b2 + l * 1024, H, 4096, 1024, 4096);
    }
    k_ln<<<dim3(4096), blk, 0, stream>>>(H, lnfg, lnfb, ABF);
    k_head<<<dim3(64, 4), blk, 0, stream>>>(ABF, HW16, out);
}